// Round 1
// baseline (147.498 us; speedup 1.0000x reference)
//
#include <hip/hip_runtime.h>

#define HIDN 512
#define NHEAD 8
#define DHEAD 64
#define NB 4
#define NL 256
#define NROW 1024   // NB*NL

// workspace layout (float offsets)
#define WS_WQF 0
#define WS_WKF (WS_WQF + HIDN*HIDN)
#define WS_BQF (WS_WKF + HIDN*HIDN)
#define WS_BKF (WS_BQF + HIDN)
#define WS_QT  (WS_BKF + HIDN)
#define WS_KT  (WS_QT + NROW*HIDN)
#define WS_VH  (WS_KT + NROW*HIDN)
#define WS_X   (WS_VH + NROW*HIDN)

// ---------------- Kernel A: fold W1/W2 into Wq/Wk ----------------
// Wq''[h*64+i, c] = sum_j W1[i,j] * Wq[h*64+j, c];  bq''[h*64+i] = W1@bq_h + b1
__global__ __launch_bounds__(256) void fuse_weights(
    const float* __restrict__ Wq, const float* __restrict__ bq,
    const float* __restrict__ Wk, const float* __restrict__ bk,
    const float* __restrict__ W1, const float* __restrict__ b1,
    const float* __restrict__ W2, const float* __restrict__ b2,
    float* __restrict__ ws)
{
  const int h = blockIdx.y;
  const int c0 = blockIdx.x * 128;
  const int which = blockIdx.z;
  const float* Wsrc = which ? Wk : Wq;
  const float* bsrc = which ? bk : bq;
  const float* Wt   = which ? W2 : W1;
  const float* bt   = which ? b2 : b1;
  float* Wout = ws + (which ? WS_WKF : WS_WQF);
  float* bout = ws + (which ? WS_BKF : WS_BQF);

  __shared__ float Wtl[64][68];
  for (int t = threadIdx.x; t < 64*64; t += 256)
    Wtl[t >> 6][t & 63] = Wt[t];
  __syncthreads();

  const int c  = c0 + (threadIdx.x & 127);
  const int i0 = (threadIdx.x >> 7) * 32;
  float acc[32];
#pragma unroll
  for (int ii = 0; ii < 32; ++ii) acc[ii] = 0.f;

  for (int j0 = 0; j0 < 64; j0 += 4) {
    const float s0 = Wsrc[(h*64 + j0 + 0)*HIDN + c];
    const float s1 = Wsrc[(h*64 + j0 + 1)*HIDN + c];
    const float s2 = Wsrc[(h*64 + j0 + 2)*HIDN + c];
    const float s3 = Wsrc[(h*64 + j0 + 3)*HIDN + c];
#pragma unroll
    for (int ii = 0; ii < 32; ++ii) {
      const float4 wv = *reinterpret_cast<const float4*>(&Wtl[i0+ii][j0]);
      float a = acc[ii];
      a = fmaf(wv.x, s0, a);
      a = fmaf(wv.y, s1, a);
      a = fmaf(wv.z, s2, a);
      a = fmaf(wv.w, s3, a);
      acc[ii] = a;
    }
  }
#pragma unroll
  for (int ii = 0; ii < 32; ++ii)
    Wout[(h*64 + i0 + ii)*HIDN + c] = acc[ii];

  if (blockIdx.x == 0 && threadIdx.x < 64) {
    const int i = threadIdx.x;
    float a = bt[i];
    for (int j = 0; j < 64; ++j)
      a = fmaf(Wtl[i][j], bsrc[h*64 + j], a);
    bout[h*64 + i] = a;
  }
}

// ---------------- GEMM body: C = A @ W^T + bias, 64x32 tile ----------------
template<bool HEADMAJOR>
__device__ __forceinline__ void gemm_body(
    const float* __restrict__ A, const float* __restrict__ W,
    const float* __restrict__ bias, float* __restrict__ C)
{
  const int row0 = blockIdx.y * 64;
  const int col0 = blockIdx.x * 32;
  __shared__ float As[16][72];
  __shared__ float Bs[16][40];
  const int tid = threadIdx.x;
  const int tx = tid & 15;   // 2 cols each
  const int ty = tid >> 4;   // 4 rows each
  float acc00=0,acc01=0,acc10=0,acc11=0,acc20=0,acc21=0,acc30=0,acc31=0;

  for (int k0 = 0; k0 < HIDN; k0 += 16) {
    {
      const int arow = tid >> 2, kq = tid & 3;
      const float4 a4 = *reinterpret_cast<const float4*>(&A[(row0+arow)*HIDN + k0 + kq*4]);
      As[kq*4+0][arow] = a4.x;
      As[kq*4+1][arow] = a4.y;
      As[kq*4+2][arow] = a4.z;
      As[kq*4+3][arow] = a4.w;
    }
    if (tid < 128) {
      const int wcol = tid >> 2, kq = tid & 3;
      const float4 w4 = *reinterpret_cast<const float4*>(&W[(col0+wcol)*HIDN + k0 + kq*4]);
      Bs[kq*4+0][wcol] = w4.x;
      Bs[kq*4+1][wcol] = w4.y;
      Bs[kq*4+2][wcol] = w4.z;
      Bs[kq*4+3][wcol] = w4.w;
    }
    __syncthreads();
#pragma unroll
    for (int kk = 0; kk < 16; ++kk) {
      const float4 av  = *reinterpret_cast<const float4*>(&As[kk][ty*4]);
      const float2 bv2 = *reinterpret_cast<const float2*>(&Bs[kk][tx*2]);
      acc00 = fmaf(av.x, bv2.x, acc00);
      acc01 = fmaf(av.x, bv2.y, acc01);
      acc10 = fmaf(av.y, bv2.x, acc10);
      acc11 = fmaf(av.y, bv2.y, acc11);
      acc20 = fmaf(av.z, bv2.x, acc20);
      acc21 = fmaf(av.z, bv2.y, acc21);
      acc30 = fmaf(av.w, bv2.x, acc30);
      acc31 = fmaf(av.w, bv2.y, acc31);
    }
    __syncthreads();
  }
  const int c = col0 + tx*2;
  const float b0 = bias[c], b1v = bias[c+1];
  const float v0[4] = {acc00+b0, acc10+b0, acc20+b0, acc30+b0};
  const float v1[4] = {acc01+b1v, acc11+b1v, acc21+b1v, acc31+b1v};
#pragma unroll
  for (int i = 0; i < 4; ++i) {
    const int row = row0 + ty*4 + i;
    const float2 v2 = make_float2(v0[i], v1[i]);
    if (HEADMAJOR) {
      const int b = row >> 8, l = row & 255;
      const int hh = c >> 6, d = c & 63;
      *reinterpret_cast<float2*>(&C[(((b*NHEAD + hh)*NL) + l)*DHEAD + d]) = v2;
    } else {
      *reinterpret_cast<float2*>(&C[row*HIDN + c]) = v2;
    }
  }
}

__global__ __launch_bounds__(256) void proj_gemm(
    const float* __restrict__ q_in, const float* __restrict__ k_in, const float* __restrict__ v_in,
    const float* __restrict__ Wv, const float* __restrict__ bv, float* __restrict__ ws)
{
  const int z = blockIdx.z;
  const float* A; const float* W; const float* bias; float* C;
  if (z == 0)      { A = q_in; W = ws + WS_WQF; bias = ws + WS_BQF; C = ws + WS_QT; }
  else if (z == 1) { A = k_in; W = ws + WS_WKF; bias = ws + WS_BKF; C = ws + WS_KT; }
  else             { A = v_in; W = Wv;          bias = bv;          C = ws + WS_VH; }
  gemm_body<true>(A, W, bias, C);
}

__global__ __launch_bounds__(256) void out_gemm(
    const float* __restrict__ X, const float* __restrict__ Wo,
    const float* __restrict__ bo, float* __restrict__ C)
{
  gemm_body<false>(X, Wo, bo, C);
}

// ---------------- Kernel C: energy + softmax + PV ----------------
// grid (16 qtiles, 32 bh), 512 threads. half = tid>>8 handles 8 q rows;
// within a half, thread lk = tid&255 owns key index lk (Kt row in registers).
__global__ __launch_bounds__(512, 4) void attn_kernel(
    const float* __restrict__ ws,
    const float* __restrict__ va_w, const float* __restrict__ va_bp,
    float* __restrict__ attn_out, float* __restrict__ X)
{
  const int qt = blockIdx.x;
  const int bh = blockIdx.y;
  const int tid = threadIdx.x;

  __shared__ float Vl[256][64];
  __shared__ float Qtl[16][64];
  __shared__ float vaS[64];
  __shared__ float aL[2][256];
  __shared__ float pp[2][4][64];
  __shared__ float redm[2][4];
  __shared__ float reds[2][4];
  __shared__ float ebS;

  const float* Qt = ws + WS_QT + (bh*NL + qt*16)*DHEAD;
  const float* Kt = ws + WS_KT + bh*NL*DHEAD;
  const float* V  = ws + WS_VH + bh*NL*DHEAD;

  for (int f = tid; f < 4096; f += 512) {
    *reinterpret_cast<float4*>(&Vl[f >> 4][(f & 15)*4]) =
        *reinterpret_cast<const float4*>(&V[f*4]);
  }
  if (tid < 256) {
    *reinterpret_cast<float4*>(&Qtl[tid >> 4][(tid & 15)*4]) =
        *reinterpret_cast<const float4*>(&Qt[tid*4]);
  }
  if (tid < 64) vaS[tid] = -2.0f * va_w[tid];
  if (tid == 0) {
    float s = va_bp[0];
    for (int j = 0; j < 64; ++j) s += va_w[j];
    ebS = s;
  }

  const int half = tid >> 8;
  const int lk = tid & 255;
  const int w = lk >> 6;
  const int l = lk & 63;

  float kreg[64];
#pragma unroll
  for (int d0 = 0; d0 < 64; d0 += 4) {
    *reinterpret_cast<float4*>(&kreg[d0]) =
        *reinterpret_cast<const float4*>(&Kt[lk*DHEAD + d0]);
  }
  __syncthreads();

  const float eb = ebS;

  for (int qi = 0; qi < 8; ++qi) {
    const int q = half*8 + qi;
    const float* qrow = Qtl[q];
    float a0=0.f, a1=0.f, a2=0.f, a3=0.f;
#pragma unroll
    for (int d0 = 0; d0 < 64; d0 += 4) {
      const float4 qv = *reinterpret_cast<const float4*>(&qrow[d0]);
      const float4 vv = *reinterpret_cast<const float4*>(&vaS[d0]);
      const float x0 = (qv.x + kreg[d0+0]) * 2.8853900817779268f; // 2*log2(e)
      const float x1 = (qv.y + kreg[d0+1]) * 2.8853900817779268f;
      const float x2 = (qv.z + kreg[d0+2]) * 2.8853900817779268f;
      const float x3 = (qv.w + kreg[d0+3]) * 2.8853900817779268f;
      a0 = fmaf(vv.x, __builtin_amdgcn_rcpf(1.0f + __builtin_amdgcn_exp2f(x0)), a0);
      a1 = fmaf(vv.y, __builtin_amdgcn_rcpf(1.0f + __builtin_amdgcn_exp2f(x1)), a1);
      a2 = fmaf(vv.z, __builtin_amdgcn_rcpf(1.0f + __builtin_amdgcn_exp2f(x2)), a2);
      a3 = fmaf(vv.w, __builtin_amdgcn_rcpf(1.0f + __builtin_amdgcn_exp2f(x3)), a3);
    }
    const float e = eb + ((a0 + a1) + (a2 + a3));

    // softmax over 256 threads of this half
    float m = e;
#pragma unroll
    for (int off = 1; off < 64; off <<= 1)
      m = fmaxf(m, __shfl_xor(m, off));
    if (l == 0) redm[half][w] = m;
    __syncthreads();
    m = fmaxf(fmaxf(redm[half][0], redm[half][1]), fmaxf(redm[half][2], redm[half][3]));
    const float p = __builtin_amdgcn_exp2f((e - m) * 1.4426950408889634f);
    float s = p;
#pragma unroll
    for (int off = 1; off < 64; off <<= 1)
      s += __shfl_xor(s, off);
    if (l == 0) reds[half][w] = s;
    __syncthreads();
    s = (reds[half][0] + reds[half][1]) + (reds[half][2] + reds[half][3]);
    const float a = p * __builtin_amdgcn_rcpf(s);

    attn_out[(bh*NL + qt*16 + q)*NL + lk] = a;
    aL[half][lk] = a;
    __syncthreads();

    // PV: wave w covers k in [w*64, w*64+64), lane l = output dim d
    float xp = 0.f;
    const int kbase = w*64;
#pragma unroll
    for (int kk = 0; kk < 64; ++kk)
      xp = fmaf(aL[half][kbase + kk], Vl[kbase + kk][l], xp);
    pp[half][w][l] = xp;
    __syncthreads();
    if (w == 0) {
      const float xv = pp[half][0][l] + pp[half][1][l] + pp[half][2][l] + pp[half][3][l];
      const int row = qt*16 + q;
      const int b = bh >> 3, hh = bh & 7;
      X[(b*NL + row)*HIDN + hh*DHEAD + l] = xv;
    }
  }
}

extern "C" void kernel_launch(void* const* d_in, const int* in_sizes, int n_in,
                              void* d_out, int out_size, void* d_ws, size_t ws_size,
                              hipStream_t stream) {
  const float* query = (const float*)d_in[0];
  const float* key   = (const float*)d_in[1];
  const float* value = (const float*)d_in[2];
  const float* Wq = (const float*)d_in[3];
  const float* bq = (const float*)d_in[4];
  const float* Wk = (const float*)d_in[5];
  const float* bk = (const float*)d_in[6];
  const float* Wv = (const float*)d_in[7];
  const float* bv = (const float*)d_in[8];
  const float* W1 = (const float*)d_in[9];
  const float* b1 = (const float*)d_in[10];
  const float* W2 = (const float*)d_in[11];
  const float* b2 = (const float*)d_in[12];
  const float* va_w = (const float*)d_in[13];
  const float* va_b = (const float*)d_in[14];
  const float* Wo = (const float*)d_in[15];
  const float* bo = (const float*)d_in[16];

  float* out = (float*)d_out;
  float* ws  = (float*)d_ws;
  float* attn = out + NROW*HIDN;   // output 1: attention [B,H,Lq,Lk]

  fuse_weights<<<dim3(4, 8, 2), 256, 0, stream>>>(Wq, bq, Wk, bk, W1, b1, W2, b2, ws);
  proj_gemm<<<dim3(16, 16, 3), 256, 0, stream>>>(query, key, value, Wv, bv, ws);
  attn_kernel<<<dim3(16, 32), 512, 0, stream>>>(ws, va_w, va_b, attn, ws + WS_X);
  out_gemm<<<dim3(16, 16), 256, 0, stream>>>(ws + WS_X, Wo, bo, out);
}

// Round 2
// 126.834 us; speedup vs baseline: 1.1629x; 1.1629x over previous
//
#include <hip/hip_runtime.h>

#define HIDN 512
#define NHEAD 8
#define DHEAD 64
#define NB 4
#define NL 256
#define NROW 1024   // NB*NL

// 2*log2(e): exp(2y) = exp2(y * SCALE2)
#define SCALE2 2.8853900817779268f
#define LOG2E  1.4426950408889634f

// workspace layout (float offsets)
#define WS_WQF 0
#define WS_WKF (WS_WQF + HIDN*HIDN)
#define WS_BQF (WS_WKF + HIDN*HIDN)
#define WS_BKF (WS_BQF + HIDN)
#define WS_QT  (WS_BKF + HIDN)
#define WS_KT  (WS_QT + NROW*HIDN)
#define WS_VH  (WS_KT + NROW*HIDN)
#define WS_X   (WS_VH + NROW*HIDN)

typedef __attribute__((ext_vector_type(4))) float f32x4;
typedef __attribute__((ext_vector_type(8))) short bf16x8;

__device__ __forceinline__ short f2bf(float x) {
  unsigned u = __float_as_uint(x);
  u += 0x7fffu + ((u >> 16) & 1u);   // RNE
  return (short)(u >> 16);
}

// ---------------- Kernel A: fold W1/W2 (and the 2*log2e prescale) into Wq/Wk ----------------
// Wq''[h*64+i, c] = SCALE2 * sum_j W1[i,j] * Wq[h*64+j, c]
// bq''[h*64+i]    = SCALE2 * (W1@bq_h + b1)[i]
// grid (4 col-chunks of 128, 8h*4 row-groups, 2 which), 256 threads
__global__ __launch_bounds__(256) void fuse_weights(
    const float* __restrict__ Wq, const float* __restrict__ bq,
    const float* __restrict__ Wk, const float* __restrict__ bk,
    const float* __restrict__ W1, const float* __restrict__ b1,
    const float* __restrict__ W2, const float* __restrict__ b2,
    float* __restrict__ ws)
{
  const int h  = blockIdx.y >> 2;
  const int ig = blockIdx.y & 3;       // 16-row group within head
  const int c0 = blockIdx.x * 128;
  const int which = blockIdx.z;
  const float* Wsrc = which ? Wk : Wq;
  const float* bsrc = which ? bk : bq;
  const float* Wt   = which ? W2 : W1;
  const float* bt   = which ? b2 : b1;
  float* Wout = ws + (which ? WS_WKF : WS_WQF);
  float* bout = ws + (which ? WS_BKF : WS_BQF);

  __shared__ float Wtl[16][68];
  for (int t = threadIdx.x; t < 16*64; t += 256)
    Wtl[t >> 6][t & 63] = Wt[(ig*16 + (t >> 6))*64 + (t & 63)];
  __syncthreads();

  const int c  = c0 + (threadIdx.x & 127);
  const int i0 = (threadIdx.x >> 7) * 8;   // local row base (0 or 8)
  float acc[8];
#pragma unroll
  for (int ii = 0; ii < 8; ++ii) acc[ii] = 0.f;

  for (int j0 = 0; j0 < 64; j0 += 4) {
    const float s0 = Wsrc[(h*64 + j0 + 0)*HIDN + c];
    const float s1 = Wsrc[(h*64 + j0 + 1)*HIDN + c];
    const float s2 = Wsrc[(h*64 + j0 + 2)*HIDN + c];
    const float s3 = Wsrc[(h*64 + j0 + 3)*HIDN + c];
#pragma unroll
    for (int ii = 0; ii < 8; ++ii) {
      const float4 wv = *reinterpret_cast<const float4*>(&Wtl[i0+ii][j0]);
      float a = acc[ii];
      a = fmaf(wv.x, s0, a);
      a = fmaf(wv.y, s1, a);
      a = fmaf(wv.z, s2, a);
      a = fmaf(wv.w, s3, a);
      acc[ii] = a;
    }
  }
#pragma unroll
  for (int ii = 0; ii < 8; ++ii)
    Wout[(h*64 + ig*16 + i0 + ii)*HIDN + c] = acc[ii] * SCALE2;

  if (blockIdx.x == 0 && threadIdx.x < 16) {
    const int il = threadIdx.x;
    float a = bt[ig*16 + il];
    for (int j = 0; j < 64; ++j)
      a = fmaf(Wtl[il][j], bsrc[h*64 + j], a);
    bout[h*64 + ig*16 + il] = a * SCALE2;
  }
}

// ---------------- proj GEMM: C = A @ W^T + bias, 64x64 tile, 4x4 micro, head-major out ----
__global__ __launch_bounds__(256) void proj_gemm(
    const float* __restrict__ q_in, const float* __restrict__ k_in, const float* __restrict__ v_in,
    const float* __restrict__ Wv, const float* __restrict__ bv, float* __restrict__ ws)
{
  const int z = blockIdx.z;
  const float* A; const float* W; const float* bias; float* C;
  if (z == 0)      { A = q_in; W = ws + WS_WQF; bias = ws + WS_BQF; C = ws + WS_QT; }
  else if (z == 1) { A = k_in; W = ws + WS_WKF; bias = ws + WS_BKF; C = ws + WS_KT; }
  else             { A = v_in; W = Wv;          bias = bv;          C = ws + WS_VH; }

  const int row0 = blockIdx.y * 64;
  const int col0 = blockIdx.x * 64;
  __shared__ float As[16][72];
  __shared__ float Bs[16][72];
  const int tid = threadIdx.x;
  const int tx = tid & 15;    // 4 cols each
  const int ty = tid >> 4;    // 4 rows each
  float acc[4][4];
#pragma unroll
  for (int i = 0; i < 4; ++i)
#pragma unroll
    for (int j = 0; j < 4; ++j) acc[i][j] = 0.f;

  const int srow = tid >> 2, kq = tid & 3;
  for (int k0 = 0; k0 < HIDN; k0 += 16) {
    {
      const float4 a4 = *reinterpret_cast<const float4*>(&A[(row0+srow)*HIDN + k0 + kq*4]);
      As[kq*4+0][srow] = a4.x; As[kq*4+1][srow] = a4.y;
      As[kq*4+2][srow] = a4.z; As[kq*4+3][srow] = a4.w;
      const float4 w4 = *reinterpret_cast<const float4*>(&W[(col0+srow)*HIDN + k0 + kq*4]);
      Bs[kq*4+0][srow] = w4.x; Bs[kq*4+1][srow] = w4.y;
      Bs[kq*4+2][srow] = w4.z; Bs[kq*4+3][srow] = w4.w;
    }
    __syncthreads();
#pragma unroll
    for (int kk = 0; kk < 16; ++kk) {
      const float4 av = *reinterpret_cast<const float4*>(&As[kk][ty*4]);
      const float4 bw = *reinterpret_cast<const float4*>(&Bs[kk][tx*4]);
      const float a_[4] = {av.x, av.y, av.z, av.w};
      const float b_[4] = {bw.x, bw.y, bw.z, bw.w};
#pragma unroll
      for (int i = 0; i < 4; ++i)
#pragma unroll
        for (int j = 0; j < 4; ++j)
          acc[i][j] = fmaf(a_[i], b_[j], acc[i][j]);
    }
    __syncthreads();
  }
  const int col = col0 + tx*4;
  const float4 b4 = *reinterpret_cast<const float4*>(&bias[col]);
  const int hh = col >> 6, d = col & 63;
#pragma unroll
  for (int i = 0; i < 4; ++i) {
    const int row = row0 + ty*4 + i;
    const int b = row >> 8, l = row & 255;
    float4 v;
    v.x = acc[i][0] + b4.x; v.y = acc[i][1] + b4.y;
    v.z = acc[i][2] + b4.z; v.w = acc[i][3] + b4.w;
    *reinterpret_cast<float4*>(&C[(((b*NHEAD + hh)*NL) + l)*DHEAD + d]) = v;
  }
}

// ---------------- out GEMM: 64x32 tile (kept from r1) ----------------
__global__ __launch_bounds__(256) void out_gemm(
    const float* __restrict__ A, const float* __restrict__ W,
    const float* __restrict__ bias, float* __restrict__ C)
{
  const int row0 = blockIdx.y * 64;
  const int col0 = blockIdx.x * 32;
  __shared__ float As[16][72];
  __shared__ float Bs[16][40];
  const int tid = threadIdx.x;
  const int tx = tid & 15;
  const int ty = tid >> 4;
  float acc00=0,acc01=0,acc10=0,acc11=0,acc20=0,acc21=0,acc30=0,acc31=0;

  for (int k0 = 0; k0 < HIDN; k0 += 16) {
    {
      const int arow = tid >> 2, kq = tid & 3;
      const float4 a4 = *reinterpret_cast<const float4*>(&A[(row0+arow)*HIDN + k0 + kq*4]);
      As[kq*4+0][arow] = a4.x; As[kq*4+1][arow] = a4.y;
      As[kq*4+2][arow] = a4.z; As[kq*4+3][arow] = a4.w;
    }
    if (tid < 128) {
      const int wcol = tid >> 2, kq = tid & 3;
      const float4 w4 = *reinterpret_cast<const float4*>(&W[(col0+wcol)*HIDN + k0 + kq*4]);
      Bs[kq*4+0][wcol] = w4.x; Bs[kq*4+1][wcol] = w4.y;
      Bs[kq*4+2][wcol] = w4.z; Bs[kq*4+3][wcol] = w4.w;
    }
    __syncthreads();
#pragma unroll
    for (int kk = 0; kk < 16; ++kk) {
      const float4 av  = *reinterpret_cast<const float4*>(&As[kk][ty*4]);
      const float2 bv2 = *reinterpret_cast<const float2*>(&Bs[kk][tx*2]);
      acc00 = fmaf(av.x, bv2.x, acc00);
      acc01 = fmaf(av.x, bv2.y, acc01);
      acc10 = fmaf(av.y, bv2.x, acc10);
      acc11 = fmaf(av.y, bv2.y, acc11);
      acc20 = fmaf(av.z, bv2.x, acc20);
      acc21 = fmaf(av.z, bv2.y, acc21);
      acc30 = fmaf(av.w, bv2.x, acc30);
      acc31 = fmaf(av.w, bv2.y, acc31);
    }
    __syncthreads();
  }
  const int c = col0 + tx*2;
  const float b0 = bias[c], b1v = bias[c+1];
  const float v0[4] = {acc00+b0, acc10+b0, acc20+b0, acc30+b0};
  const float v1[4] = {acc01+b1v, acc11+b1v, acc21+b1v, acc31+b1v};
#pragma unroll
  for (int i = 0; i < 4; ++i) {
    const int row = row0 + ty*4 + i;
    *reinterpret_cast<float2*>(&C[row*HIDN + c]) = make_float2(v0[i], v1[i]);
  }
}

// ---------------- attn: energy + (no-max) softmax + MFMA PV ----------------
// grid (16 qtiles, 32 bh), 512 threads. Thread (h=tid>>8, lk=tid&255) owns key lk
// for q-rows h*8..h*8+7. Logits |e| <= 2*sum|va| ~ 8 -> softmax without max.
__global__ __launch_bounds__(512, 6) void attn_kernel(
    const float* __restrict__ ws, const float* __restrict__ va_w,
    float* __restrict__ attn_out, float* __restrict__ X)
{
  const int qt = blockIdx.x;
  const int bh = blockIdx.y;
  const int tid = threadIdx.x;

  // MFMA-fragment-major stores: tile = (k>>5)*4 + (d>>4); lane = ((k>>3)&3)*16 + (d&15); j = k&7
  __shared__ __align__(16) short Vfrag[32][64][8];   // 32 KB  V as bf16 B-fragments
  __shared__ __align__(16) short aLb[8][64][8];      // 8 KB   P as bf16 A-fragments (kb-major)
  __shared__ __align__(16) float Qtl[16][64];        // 4 KB
  __shared__ __align__(16) float vaS[64];
  __shared__ __align__(16) float reds[2][4][8];

  const float* Qt  = ws + WS_QT + (bh*NL + qt*16)*DHEAD;
  const float* KtB = ws + WS_KT + bh*NL*DHEAD;
  const float* V   = ws + WS_VH + bh*NL*DHEAD;

  // stage V into fragment layout (bf16)
  for (int f = tid; f < 4096; f += 512) {
    const int k = f >> 4, d0 = (f & 15) * 4;
    const float4 v4 = *reinterpret_cast<const float4*>(&V[k*DHEAD + d0]);
    const int tile = (k >> 5)*4 + (d0 >> 4);
    const int lb = ((k >> 3) & 3) * 16 + (d0 & 15);
    const int j = k & 7;
    Vfrag[tile][lb+0][j] = f2bf(v4.x);
    Vfrag[tile][lb+1][j] = f2bf(v4.y);
    Vfrag[tile][lb+2][j] = f2bf(v4.z);
    Vfrag[tile][lb+3][j] = f2bf(v4.w);
  }
  if (tid < 256)
    reinterpret_cast<float4*>(Qtl)[tid] = reinterpret_cast<const float4*>(Qt)[tid];
  if (tid < 64) vaS[tid] = -2.0f * va_w[tid];
  __syncthreads();

  const int h  = tid >> 8;
  const int lk = tid & 255;
  const int wv = lk >> 6;
  const int l  = lk & 63;
  const float* KtRow = KtB + lk*DHEAD;

  float acc[8];
#pragma unroll
  for (int qi = 0; qi < 8; ++qi) acc[qi] = 0.f;

#pragma unroll 1
  for (int d0g = 0; d0g < 64; d0g += 16) {
#pragma unroll
    for (int dc = 0; dc < 16; dc += 4) {
      const int d0 = d0g + dc;
      const float4 kt  = *reinterpret_cast<const float4*>(KtRow + d0);
      const float4 va4 = *reinterpret_cast<const float4*>(&vaS[d0]);
#pragma unroll
      for (int qi = 0; qi < 8; ++qi) {
        const float4 qv = *reinterpret_cast<const float4*>(&Qtl[h*8+qi][d0]);
        float a = acc[qi];
        a = fmaf(va4.x, __builtin_amdgcn_rcpf(1.0f + __builtin_amdgcn_exp2f(qv.x + kt.x)), a);
        a = fmaf(va4.y, __builtin_amdgcn_rcpf(1.0f + __builtin_amdgcn_exp2f(qv.y + kt.y)), a);
        a = fmaf(va4.z, __builtin_amdgcn_rcpf(1.0f + __builtin_amdgcn_exp2f(qv.z + kt.z)), a);
        a = fmaf(va4.w, __builtin_amdgcn_rcpf(1.0f + __builtin_amdgcn_exp2f(qv.w + kt.w)), a);
        acc[qi] = a;
      }
    }
  }

  // p = exp(e) (no max needed; |e| <= ~8), wave-level partial sums
  float p[8];
#pragma unroll
  for (int qi = 0; qi < 8; ++qi)
    p[qi] = __builtin_amdgcn_exp2f(acc[qi] * LOG2E);

  float ssum[8];
#pragma unroll
  for (int qi = 0; qi < 8; ++qi) {
    float s = p[qi];
#pragma unroll
    for (int off = 1; off < 64; off <<= 1)
      s += __shfl_xor(s, off);
    ssum[qi] = s;
  }
  if (l == 0) {
#pragma unroll
    for (int qi = 0; qi < 8; ++qi) reds[h][wv][qi] = ssum[qi];
  }
  // publish P as bf16 A-fragments
  {
    const int kb = lk >> 5;
    const int lbase = ((lk >> 3) & 3) * 16;
    const int jb = lk & 7;
#pragma unroll
    for (int qi = 0; qi < 8; ++qi)
      aLb[kb][lbase + h*8 + qi][jb] = f2bf(p[qi]);
  }
  __syncthreads();

  // totals + attention output (f32 exact path)
  {
    f32x4 slo = {0.f,0.f,0.f,0.f}, shi = {0.f,0.f,0.f,0.f};
#pragma unroll
    for (int w2 = 0; w2 < 4; ++w2) {
      slo += *reinterpret_cast<const f32x4*>(&reds[h][w2][0]);
      shi += *reinterpret_cast<const f32x4*>(&reds[h][w2][4]);
    }
    float inv[8];
    inv[0] = __builtin_amdgcn_rcpf(slo.x); inv[1] = __builtin_amdgcn_rcpf(slo.y);
    inv[2] = __builtin_amdgcn_rcpf(slo.z); inv[3] = __builtin_amdgcn_rcpf(slo.w);
    inv[4] = __builtin_amdgcn_rcpf(shi.x); inv[5] = __builtin_amdgcn_rcpf(shi.y);
    inv[6] = __builtin_amdgcn_rcpf(shi.z); inv[7] = __builtin_amdgcn_rcpf(shi.w);
#pragma unroll
    for (int qi = 0; qi < 8; ++qi)
      attn_out[(bh*NL + qt*16 + h*8 + qi)*NL + lk] = p[qi] * inv[qi];

    // PV via MFMA: 4 waves, wave w = d-block, 8 chained k-blocks
    const int wid = tid >> 6;
    if (wid < 4) {
      f32x4 pacc = {0.f,0.f,0.f,0.f};
#pragma unroll
      for (int kb2 = 0; kb2 < 8; ++kb2) {
        const bf16x8 af = *reinterpret_cast<const bf16x8*>(&aLb[kb2][l][0]);
        const bf16x8 bff = *reinterpret_cast<const bf16x8*>(&Vfrag[kb2*4 + wid][l][0]);
        pacc = __builtin_amdgcn_mfma_f32_16x16x32_bf16(af, bff, pacc, 0, 0, 0);
      }
      const int b_ = bh >> 3, hh = bh & 7;
      const int colv = hh*DHEAD + wid*16 + (l & 15);
      const float sinv[4] = {inv[0], inv[1], inv[2], inv[3]};
      (void)sinv;
#pragma unroll
      for (int r = 0; r < 4; ++r) {
        const int row = (l >> 4)*4 + r;            // q index 0..15
        // normalize: need 1/s for row; rows 0..15 map across halves (h of that q = row>>3)
        // PV accumulated UNNORMALIZED p, so scale by 1/s(row): read from reds
        float stot = reds[row>>3][0][row&7] + reds[row>>3][1][row&7]
                   + reds[row>>3][2][row&7] + reds[row>>3][3][row&7];
        X[((b_*NL + qt*16 + row)*HIDN) + colv] = pacc[r] * __builtin_amdgcn_rcpf(stot);
      }
    }
  }
}

extern "C" void kernel_launch(void* const* d_in, const int* in_sizes, int n_in,
                              void* d_out, int out_size, void* d_ws, size_t ws_size,
                              hipStream_t stream) {
  const float* query = (const float*)d_in[0];
  const float* key   = (const float*)d_in[1];
  const float* value = (const float*)d_in[2];
  const float* Wq = (const float*)d_in[3];
  const float* bq = (const float*)d_in[4];
  const float* Wk = (const float*)d_in[5];
  const float* bk = (const float*)d_in[6];
  const float* Wv = (const float*)d_in[7];
  const float* bv = (const float*)d_in[8];
  const float* W1 = (const float*)d_in[9];
  const float* b1 = (const float*)d_in[10];
  const float* W2 = (const float*)d_in[11];
  const float* b2 = (const float*)d_in[12];
  const float* va_w = (const float*)d_in[13];
  const float* Wo = (const float*)d_in[15];
  const float* bo = (const float*)d_in[16];

  float* out = (float*)d_out;
  float* ws  = (float*)d_ws;
  float* attn = out + NROW*HIDN;   // output 1: attention [B,H,Lq,Lk]

  fuse_weights<<<dim3(4, 32, 2), 256, 0, stream>>>(Wq, bq, Wk, bk, W1, b1, W2, b2, ws);
  proj_gemm<<<dim3(8, 16, 3), 256, 0, stream>>>(query, key, value, Wv, bv, ws);
  attn_kernel<<<dim3(16, 32), 512, 0, stream>>>(ws, va_w, attn, ws + WS_X);
  out_gemm<<<dim3(16, 16), 256, 0, stream>>>(ws + WS_X, Wo, bo, out);
}